// Round 18
// baseline (90.122 us; speedup 1.0000x reference)
//
#include <hip/hip_runtime.h>
#include <math.h>

#define CIN   64
#define COUT  128
#define HW    56
#define L_    3136
#define KTOT  6912
#define TH    8            // tile rows
#define TW    8            // tile cols
#define HALO_W 10
#define NPIX  100          // 10 x 10 halo pixels
#define CSTR  (NPIX*16 + 32)  // 1632 B stride
#define G8_SIZE (8*CSTR)   // 13056
#define G4_SIZE (4*CSTR)   // 6528
#define BUF_SIZE (G8_SIZE+G4_SIZE) // 19584; x2 dbuf = 39168 B/block

#define BP_BYTES (COUT * KTOT * 2)        // 1,769,472 (432 k16-panels x 4096B)
#define PART_OFF BP_BYTES
#define SS_OFF   (PART_OFF + 2048 * 4)

typedef __attribute__((ext_vector_type(8)))  short bf16x8;
typedef __attribute__((ext_vector_type(16))) float f32x16;
typedef unsigned long long u64;

#define BLOAD(dst, addr) \
    asm volatile("global_load_dwordx4 %0, %1, off" : "=v"(dst) : "v"(addr))
#define XLOAD(dst, addr) \
    asm volatile("global_load_dword %0, %1, off" : "=v"(dst) : "v"(addr))

__device__ __forceinline__ unsigned short f2bf(float f) {
    unsigned int u = __float_as_uint(f);
    return (unsigned short)((u + 0x7FFFu + ((u >> 16) & 1u)) >> 16);   // RNE
}
__device__ __forceinline__ unsigned int pk2(float a, float b) {
    return (unsigned int)f2bf(a) | ((unsigned int)f2bf(b) << 16);
}

// Reference basis for one pixel. g8rec built in registers, ONE b128 write;
// g4half (8B) = {f8, f9, f10, raw x}.
__device__ __forceinline__ void eval_store(float xv, char* g8rec, char* g4half) {
    float u  = 1.0f / (1.0f + __expf(-xv));
    float tt = u * 11.0f;
    int s = (int)floorf(tt);
    s = (s > 10) ? 10 : s;
    float xf  = tt - (float)s;
    float x2  = xf * xf, x3 = x2 * xf;
    float omx = 1.0f - xf;
    const float i6 = 1.0f / 6.0f;
    float w3 = x3 * i6;
    float w2 = fmaf(fmaf(fmaf(-3.0f, xf, 3.0f), xf, 3.0f), xf, 1.0f) * i6;
    float w1 = fmaf(fmaf(3.0f, xf, -6.0f), x2, 4.0f) * i6;
    float w0 = omx * omx * omx * i6;

    unsigned int b0 = f2bf(w0), b1 = f2bf(w1), b2 = f2bf(w2), b3 = f2bf(w3);
    unsigned int slot[8];
#pragma unroll
    for (int j = 0; j < 8; j++) {
        unsigned int v = 0;
        v = (s == j)     ? b3 : v;
        v = (s == j + 1) ? b2 : v;
        v = (s == j + 2) ? b1 : v;
        v = (s == j + 3) ? b0 : v;
        slot[j] = v;
    }
    uint4 rec;
    rec.x = slot[0] | (slot[1] << 16);
    rec.y = slot[2] | (slot[3] << 16);
    rec.z = slot[4] | (slot[5] << 16);
    rec.w = slot[6] | (slot[7] << 16);
    *reinterpret_cast<uint4*>(g8rec) = rec;

    float y = tt - 8.0f;
    float f8 = 0.0f;
    f8 = (s == 8)  ? 0.5f * y * y : f8;
    f8 = (s == 9)  ? 0.5f * fmaf(-2.0f * y, y, fmaf(6.0f, y, -3.0f)) : f8;
    f8 = (s == 10) ? 0.5f * (3.0f - y) * (3.0f - y) : f8;
    float z = tt - 9.0f;
    float f9 = 0.0f;
    f9 = (s == 9)  ? z : f9;
    f9 = (s == 10) ? 2.0f - z : f9;
    float f10 = (s == 10) ? 1.0f : 0.0f;
    *reinterpret_cast<uint2*>(g4half) = make_uint2(pk2(f8, f9), pk2(f10, xv));
}

// Pack B as per-(k16step, o) 16-elem rows: Bp[k16][o][e16], panel = 4096 B.
// k16 = ch*54 + s ; g32 = s>>1, khalf = s&1, ktap = g32/3, ph = g32%3,
// e32 = khalf*16 + e16 ; (c,n) from e32 exactly as the old 32-elem order.
__global__ __launch_bounds__(256) void k_packB(const float* __restrict__ cp,
                                               const float* __restrict__ w,
                                               unsigned short* __restrict__ Bp) {
    int idx = blockIdx.x * 256 + threadIdx.x;
    if (idx >= COUT * KTOT) return;
    int k16 = idx >> 11;              // /2048 (128 o x 16 e)
    int rem = idx & 2047;
    int o   = rem >> 4;
    int e16 = rem & 15;
    int ch  = k16 / 54, s54 = k16 - ch * 54;
    int g32 = s54 >> 1, khalf = s54 & 1;
    int ktap = g32 / 3, ph = g32 - ktap * 3;
    int e32 = khalf * 16 + e16;
    int c, n;
    if (ph < 2) { c = ch * 8 + ph * 4 + (e32 >> 3); n = e32 & 7; }
    else        { int sub = e32 & 7; c = ch * 8 + (e32 >> 3) * 2 + (sub >> 2); n = 8 + (sub & 3); }
    float v;
    if (n < 11) v = cp[(((size_t)o * CIN + c) * 9 + ktap) * 11 + n];
    else        v = w[((size_t)o * CIN + c) * 9 + ktap];
    Bp[idx] = f2bf(v);
}

// 32x32x16 MFMA main kernel. Waves: 2 m-halves x 2 o-halves. Per K16-step:
// ONE A ds_read (row = lane&31 of this wave's 32 rows, k = (lane>>5)*8+e),
// TWO B streams (otiles om*2, om*2+1; col = lane&31, k = (lane>>5)*8+e),
// TWO MFMAs. Pipeline structure (2 streams, 9-deep, vmcnt(16), flat arrays)
// is byte-identical in shape to the proven R11/R15/R16 kernels.
__global__ __launch_bounds__(256) void k_main(const float* __restrict__ x,
                                              const unsigned short* __restrict__ Bp,
                                              float* __restrict__ out,
                                              float* __restrict__ part) {
    __shared__ char lds[2 * BUF_SIZE];

    const int bid  = blockIdx.x;
    // XCD swizzle: 392 = 8*49; one image per XCD -> x+B L2-resident.
    const int b    = bid & 7;
    const int tile = bid >> 3;            // 0..48
    const int th   = tile / 7;
    const int tw   = tile - th * 7;
    const int t    = threadIdx.x;
    const int lane = t & 63;
    const int wid  = t >> 6;
    const int mh   = wid >> 1;            // m-half: rows mh*32..mh*32+31
    const int om   = wid & 1;             // o-half: otiles om*2, om*2+1

    // ---- staging roles: 800 (pixel,channel) pairs per chunk, 4 slots/thread
    const bool valid = (t < 200);
    const int p     = (t < 100) ? t : (t - 100);
    const int hi100 = (t >= 100) ? 1 : 0;
    const int ph_  = p / 10, pw_ = p - ph_ * 10;
    const int hg = th * TH - 1 + ph_;
    const int wg = tw * TW - 1 + pw_;
    const bool inb = valid && (hg >= 0) && (hg < HW) && (wg >= 0) && (wg < HW);
    const u64 xadv = inb ? (u64)8 * L_ * 4 : 0;
    u64 px[4];
#pragma unroll
    for (int r = 0; r < 4; r++) {
        int c0 = 2 * r + hi100;
        px[r] = inb ? ((u64)x + (((u64)b * CIN + c0) * L_ + (u64)hg * HW + wg) * 4)
                    : (u64)x;
    }

    // ---- MFMA lane invariants ----
    const int l31 = lane & 31;
    const int lh5 = lane >> 5;            // k-half selector
    int P0;
    {
        int row = mh * 32 + l31;
        int lh = row >> 3, lw = row & 7;
        P0 = (lh * HALO_W + lw) * 16 + lh5 * CSTR;
    }

    // B running pointers: 2 otile streams; per-step panel stride 4096 B.
    const u64 bend = (u64)Bp + BP_BYTES;
    u64 pa0 = (u64)Bp + (u64)((om * 2 + 0) * 32 + l31) * 32 + (u64)lh5 * 16;
    u64 pa1 = (u64)Bp + (u64)((om * 2 + 1) * 32 + l31) * 32 + (u64)lh5 * 16;

    f32x16 acc0, acc1;
#pragma unroll
    for (int i = 0; i < 16; i++) { acc0[i] = 0.f; acc1[i] = 0.f; }

    // ---- chunk-0 x loads + eval ----
    float xa[4];
    XLOAD(xa[0], px[0]); XLOAD(xa[1], px[1]);
    XLOAD(xa[2], px[2]); XLOAD(xa[3], px[3]);
#pragma unroll
    for (int r = 0; r < 4; r++) px[r] += xadv;   // -> chunk-1 channels
    asm volatile("s_waitcnt vmcnt(0)");
    __builtin_amdgcn_sched_barrier(0);
    if (valid) {
#pragma unroll
        for (int r = 0; r < 4; r++) {
            float va = inb ? xa[r] : 0.0f;
            int c = 2 * r + hi100;
            eval_store(va, &lds[c * CSTR + p * 16],
                       &lds[G8_SIZE + r * CSTR + p * 16 + hi100 * 8]);
        }
    }
    __syncthreads();

    // ---- B pipeline prologue: 9 pairs in flight ----
    bf16x8 breg0[9], breg1[9];
#pragma unroll
    for (int s = 0; s < 9; s++) {
        BLOAD(breg0[s], pa0);
        BLOAD(breg1[s], pa1);
        pa0 += 4096; pa1 += 4096;
    }

    bf16x8 areg[3];

#pragma unroll 1
    for (int ch = 0; ch < 8; ch++) {
        // x quad for chunk ch+1 (ch==7: dummy reload of chunk-7, in bounds)
        XLOAD(xa[0], px[0]); XLOAD(xa[1], px[1]);
        XLOAD(xa[2], px[2]); XLOAD(xa[3], px[3]);
        if (ch < 6) {                      // keep px in bounds for dummy reload
#pragma unroll
            for (int r = 0; r < 4; r++) px[r] += xadv;
        }

        char* abuf = &lds[(ch & 1) * BUF_SIZE];
        char* nbuf = &lds[((ch + 1) & 1) * BUF_SIZE];

        // A read for K16-step s (0..53): g32=s>>1, khalf=s&1;
        // ph<2: channel-record (ph*4 + khalf*2 + lh5), else g4 record.
#define AREAD(ss, slot) do { \
        int g32_ = (ss) >> 1, kh_ = (ss) & 1; \
        int kt_ = g32_ / 3, ph2_ = g32_ - kt_ * 3; \
        int ki_ = kt_ / 3, kj_ = kt_ - ki_ * 3; \
        int poff_ = (ki_ * HALO_W + kj_) * 16; \
        int aoff_ = (ph2_ == 2) ? (G8_SIZE + (kh_ * 2) * CSTR + poff_) \
                                : ((ph2_ * 4 + kh_ * 2) * CSTR + poff_); \
        areg[slot] = *reinterpret_cast<const bf16x8*>(abuf + P0 + aoff_); \
    } while (0)

        AREAD(0, 0);
        AREAD(1, 1);

#pragma unroll
        for (int s = 0; s < 54; s++) {
            // Post-drain queue: outstanding = 4 + 2s; vmcnt(16) retires the
            // consumed pair (refilled at s-9, or prologue) with margin, and
            // the x quad by s==9 (before the eval below).
            asm volatile("s_waitcnt vmcnt(16)");
            __builtin_amdgcn_sched_barrier(0);
            const int bs = s % 9;
            const int cs = s % 3;
            acc0 = __builtin_amdgcn_mfma_f32_32x32x16_bf16(areg[cs], breg0[bs], acc0, 0, 0, 0);
            acc1 = __builtin_amdgcn_mfma_f32_32x32x16_bf16(areg[cs], breg1[bs], acc1, 0, 0, 0);
            // A-prefetch for step s+2 (slot (s+2)%3 != cs)
            if (s + 2 < 54) AREAD(s + 2, (s + 2) % 3);
            // refill consumed pair for step s+9 (tail wraps past Bp end ->
            // start; wrapped values never consumed)
            BLOAD(breg0[bs], pa0);
            BLOAD(breg1[bs], pa1);
            pa0 += 4096; if (pa0 >= bend) pa0 -= BP_BYTES;
            pa1 += 4096; if (pa1 >= bend) pa1 -= BP_BYTES;
        }
#undef AREAD

        if (ch < 7 && valid) {
#pragma unroll
            for (int r = 0; r < 4; r++) {
                float va = inb ? xa[r] : 0.0f;
                int c = 2 * r + hi100;
                eval_store(va, &nbuf[c * CSTR + p * 16],
                           &nbuf[G8_SIZE + r * CSTR + p * 16 + hi100 * 8]);
            }
        }
        __syncthreads();   // full fence: drains vmem+lds, orders LDS reuse
    }

    // ---- epilogue: store + fused BN partial stats ----
    // D col = o = otile*32 + l31 ; D row = mh*32 + (reg&3) + 8*(reg>>2) + 4*lh5
    float psum[2] = {0.f, 0.f}, psq[2] = {0.f, 0.f};
#pragma unroll
    for (int j = 0; j < 2; j++) {
        const f32x16& a = j ? acc1 : acc0;
        int o = (om * 2 + j) * 32 + l31;
#pragma unroll
        for (int q4 = 0; q4 < 4; q4++) {
            int lh  = mh * 4 + q4;
            int lw0 = 4 * lh5;
            int lg = (th * TH + lh) * HW + tw * TW + lw0;
            float4 v;
            v.x = a[4 * q4 + 0];
            v.y = a[4 * q4 + 1];
            v.z = a[4 * q4 + 2];
            v.w = a[4 * q4 + 3];
            *reinterpret_cast<float4*>(&out[(size_t)(b * COUT + o) * L_ + lg]) = v;
            psum[j] += v.x + v.y + v.z + v.w;
            psq[j]  += v.x * v.x + v.y * v.y + v.z * v.z + v.w * v.w;
        }
    }
    // lanes l and l+32 share o -> one xor-32 reduce, lane<32 commits
#pragma unroll
    for (int j = 0; j < 2; j++) {
        psum[j] += __shfl_xor(psum[j], 32);
        psq[j]  += __shfl_xor(psq[j], 32);
    }
    if (lh5 == 0) {
#pragma unroll
        for (int j = 0; j < 2; j++) {
            int o = (om * 2 + j) * 32 + l31;
            atomicAdd(&part[b * COUT + o], psum[j]);
            atomicAdd(&part[1024 + b * COUT + o], psq[j]);
        }
    }
}

__global__ __launch_bounds__(128) void k_final(const float* __restrict__ part,
                                               const float* __restrict__ gamma,
                                               const float* __restrict__ beta,
                                               float* __restrict__ ss) {
    int o = threadIdx.x;
    float sum = 0.f, sq = 0.f;
#pragma unroll
    for (int b = 0; b < 8; b++) {
        sum += part[b * COUT + o];
        sq  += part[1024 + b * COUT + o];
    }
    float n = (float)(8 * L_);
    float mean = sum / n;
    float var  = sq / n - mean * mean;
    float scale = gamma[o] * rsqrtf(var + 1e-5f);
    ss[o]        = scale;
    ss[COUT + o] = beta[o] - mean * scale;
}

__global__ __launch_bounds__(256) void k_norm(float* __restrict__ out,
                                              const float* __restrict__ ss) {
    const int n4 = 8 * COUT * L_ / 4;
    for (int i = blockIdx.x * 256 + threadIdx.x; i < n4; i += gridDim.x * 256) {
        int o = ((i * 4) / L_) & (COUT - 1);
        float sc = ss[o], sh = ss[COUT + o];
        float4 v = reinterpret_cast<float4*>(out)[i];
        v.x = fmaf(v.x, sc, sh);
        v.y = fmaf(v.y, sc, sh);
        v.z = fmaf(v.z, sc, sh);
        v.w = fmaf(v.w, sc, sh);
        reinterpret_cast<float4*>(out)[i] = v;
    }
}

extern "C" void kernel_launch(void* const* d_in, const int* in_sizes, int n_in,
                              void* d_out, int out_size, void* d_ws, size_t ws_size,
                              hipStream_t stream) {
    const float* x     = (const float*)d_in[0];
    const float* cp    = (const float*)d_in[1];
    const float* w     = (const float*)d_in[2];
    const float* gamma = (const float*)d_in[4];
    const float* beta  = (const float*)d_in[5];
    float* out = (float*)d_out;

    unsigned short* Bp = (unsigned short*)d_ws;
    float* part = (float*)((char*)d_ws + PART_OFF);
    float* ss   = (float*)((char*)d_ws + SS_OFF);

    hipMemsetAsync(part, 0, 2048 * sizeof(float), stream);
    k_packB<<<(COUT * KTOT + 255) / 256, 256, 0, stream>>>(cp, w, Bp);
    k_main<<<8 * 49, 256, 0, stream>>>(x, Bp, out, part);
    k_final<<<1, 128, 0, stream>>>(part, gamma, beta, ss);
    k_norm<<<2048, 256, 0, stream>>>(out, ss);
}

// Round 20
// 78.009 us; speedup vs baseline: 1.1553x; 1.1553x over previous
//
#include <hip/hip_runtime.h>
#include <math.h>

#define CIN   64
#define COUT  128
#define HW    56
#define L_    3136
#define KTOT  6912
#define TH    8            // tile rows
#define TW    8            // tile cols
#define HALO_W 10
#define NPIX  100          // 10 x 10 halo pixels
#define CSTR  (NPIX*16 + 32)  // 1632 B stride (R11-proven)
#define G8_SIZE (8*CSTR)   // 13056
#define G4_SIZE (4*CSTR)   // 6528
#define BUF_SIZE (G8_SIZE+G4_SIZE) // 19584; x2 dbuf = 39168 B/block

#define BP_BYTES (COUT * KTOT * 2)        // 1,769,472
#define PART_OFF BP_BYTES
#define SS_OFF   (PART_OFF + 2048 * 4)

typedef __attribute__((ext_vector_type(8))) short bf16x8;
typedef __attribute__((ext_vector_type(4))) float f32x4;
typedef unsigned long long u64;

#define BLOAD(dst, addr) \
    asm volatile("global_load_dwordx4 %0, %1, off" : "=v"(dst) : "v"(addr))
#define XLOAD(dst, addr) \
    asm volatile("global_load_dword %0, %1, off" : "=v"(dst) : "v"(addr))

__device__ __forceinline__ unsigned short f2bf(float f) {
    unsigned int u = __float_as_uint(f);
    return (unsigned short)((u + 0x7FFFu + ((u >> 16) & 1u)) >> 16);   // RNE
}
__device__ __forceinline__ unsigned int pk2(float a, float b) {
    return (unsigned int)f2bf(a) | ((unsigned int)f2bf(b) << 16);
}

// Reference basis for one pixel. g8rec built in registers, ONE b128 write;
// g4half (8B) = {f8, f9, f10, raw x}.
__device__ __forceinline__ void eval_store(float xv, char* g8rec, char* g4half) {
    float u  = 1.0f / (1.0f + __expf(-xv));
    float tt = u * 11.0f;
    int s = (int)floorf(tt);
    s = (s > 10) ? 10 : s;
    float xf  = tt - (float)s;
    float x2  = xf * xf, x3 = x2 * xf;
    float omx = 1.0f - xf;
    const float i6 = 1.0f / 6.0f;
    float w3 = x3 * i6;
    float w2 = fmaf(fmaf(fmaf(-3.0f, xf, 3.0f), xf, 3.0f), xf, 1.0f) * i6;
    float w1 = fmaf(fmaf(3.0f, xf, -6.0f), x2, 4.0f) * i6;
    float w0 = omx * omx * omx * i6;

    unsigned int b0 = f2bf(w0), b1 = f2bf(w1), b2 = f2bf(w2), b3 = f2bf(w3);
    unsigned int slot[8];
#pragma unroll
    for (int j = 0; j < 8; j++) {
        unsigned int v = 0;
        v = (s == j)     ? b3 : v;
        v = (s == j + 1) ? b2 : v;
        v = (s == j + 2) ? b1 : v;
        v = (s == j + 3) ? b0 : v;
        slot[j] = v;
    }
    uint4 rec;
    rec.x = slot[0] | (slot[1] << 16);
    rec.y = slot[2] | (slot[3] << 16);
    rec.z = slot[4] | (slot[5] << 16);
    rec.w = slot[6] | (slot[7] << 16);
    *reinterpret_cast<uint4*>(g8rec) = rec;

    float y = tt - 8.0f;
    float f8 = 0.0f;
    f8 = (s == 8)  ? 0.5f * y * y : f8;
    f8 = (s == 9)  ? 0.5f * fmaf(-2.0f * y, y, fmaf(6.0f, y, -3.0f)) : f8;
    f8 = (s == 10) ? 0.5f * (3.0f - y) * (3.0f - y) : f8;
    float z = tt - 9.0f;
    float f9 = 0.0f;
    f9 = (s == 9)  ? z : f9;
    f9 = (s == 10) ? 2.0f - z : f9;
    float f10 = (s == 10) ? 1.0f : 0.0f;
    *reinterpret_cast<uint2*>(g4half) = make_uint2(pk2(f8, f9), pk2(f10, xv));
}

// Pack B in DENSE per-(kstep,o) 64B units: Bp[kstep][o][e32] (R6-proven).
// Also zeroes the 2048-float `part` buffer (replaces the memset launch;
// same-stream ordering guarantees it completes before k_main's atomics).
__global__ __launch_bounds__(256) void k_packB(const float* __restrict__ cp,
                                               const float* __restrict__ w,
                                               unsigned short* __restrict__ Bp,
                                               float* __restrict__ part) {
    int idx = blockIdx.x * 256 + threadIdx.x;
    if (idx < 2048) part[idx] = 0.0f;
    if (idx >= COUT * KTOT) return;
    int kstep = idx >> 12;
    int rem   = idx & 4095;
    int o     = rem >> 5;
    int e32   = rem & 31;
    int ch = kstep / 27, sc = kstep - ch * 27;
    int ktap = sc / 3, ph = sc - ktap * 3;
    int c, n;
    if (ph < 2) { c = ch * 8 + ph * 4 + (e32 >> 3); n = e32 & 7; }
    else        { int sub = e32 & 7; c = ch * 8 + (e32 >> 3) * 2 + (sub >> 2); n = 8 + (sub & 3); }
    float v;
    if (n < 11) v = cp[(((size_t)o * CIN + c) * 9 + ktap) * 11 + n];
    else        v = w[((size_t)o * CIN + c) * 9 + ktap];
    Bp[idx] = f2bf(v);
}

// R16-proven main kernel (best passing: k_main ~72us). Full-K GEMM per tile,
// 4 o-quarter waves, dense-B register pipeline (2 streams, 9-deep pairs,
// vmcnt(16)), XCD-swizzled blocks, fused BN partial stats. Bias omitted
// (cancels exactly in BN; conv_b is zeros anyway).
__global__ __launch_bounds__(256) void k_main(const float* __restrict__ x,
                                              const unsigned short* __restrict__ Bp,
                                              float* __restrict__ out,
                                              float* __restrict__ part) {
    __shared__ char lds[2 * BUF_SIZE];

    const int bid  = blockIdx.x;
    // XCD swizzle: 392 = 8*49; one image per XCD -> x+B L2-resident.
    const int b    = bid & 7;
    const int tile = bid >> 3;            // 0..48
    const int th   = tile / 7;
    const int tw   = tile - th * 7;
    const int t    = threadIdx.x;
    const int lane = t & 63;
    const int wid  = t >> 6;              // 0..3 : o-quarter

    // ---- staging roles: 800 (pixel,channel) pairs per chunk, 4 slots/thread
    const bool valid = (t < 200);
    const int p     = (t < 100) ? t : (t - 100);
    const int hi100 = (t >= 100) ? 1 : 0;
    const int ph_  = p / 10, pw_ = p - ph_ * 10;
    const int hg = th * TH - 1 + ph_;
    const int wg = tw * TW - 1 + pw_;
    const bool inb = valid && (hg >= 0) && (hg < HW) && (wg >= 0) && (wg < HW);
    const u64 xadv = inb ? (u64)8 * L_ * 4 : 0;
    u64 px[4];
#pragma unroll
    for (int r = 0; r < 4; r++) {
        int c0 = 2 * r + hi100;
        px[r] = inb ? ((u64)x + (((u64)b * CIN + c0) * L_ + (u64)hg * HW + wg) * 4)
                    : (u64)x;
    }

    // ---- MFMA lane invariants ----
    const int q   = lane >> 4;
    const int r15 = lane & 15;
    int P[4];
#pragma unroll
    for (int mi = 0; mi < 4; mi++) {
        int lh = mi * 2 + (r15 >> 3);
        int lw = r15 & 7;
        P[mi] = (lh * HALO_W + lw) * 16 + q * CSTR;
    }
    const int obase = wid * 32 + r15;

    // B running pointers, dense layout; per-step stride 8192B, wrap at end.
    const u64 bend = (u64)Bp + BP_BYTES;
    u64 pa0 = (u64)Bp + ((u64)obase * 64) + ((u64)q * 16);
    u64 pa1 = pa0 + 1024;                 // +16 o

    f32x4 acc[4][2];
#pragma unroll
    for (int mi = 0; mi < 4; mi++)
#pragma unroll
        for (int ni = 0; ni < 2; ni++) acc[mi][ni] = (f32x4){0.f, 0.f, 0.f, 0.f};

    // ---- chunk-0 x loads + eval ----
    float xa[4];
    XLOAD(xa[0], px[0]); XLOAD(xa[1], px[1]);
    XLOAD(xa[2], px[2]); XLOAD(xa[3], px[3]);
#pragma unroll
    for (int r = 0; r < 4; r++) px[r] += xadv;   // -> chunk-1 channels
    asm volatile("s_waitcnt vmcnt(0)");
    __builtin_amdgcn_sched_barrier(0);
    if (valid) {
#pragma unroll
        for (int r = 0; r < 4; r++) {
            float va = inb ? xa[r] : 0.0f;
            int c = 2 * r + hi100;
            eval_store(va, &lds[c * CSTR + p * 16],
                       &lds[G8_SIZE + r * CSTR + p * 16 + hi100 * 8]);
        }
    }
    __syncthreads();

    // ---- B pipeline prologue: 9 pairs in flight ----
    bf16x8 breg0[9], breg1[9];
#pragma unroll
    for (int s = 0; s < 9; s++) {
        BLOAD(breg0[s], pa0);
        BLOAD(breg1[s], pa1);
        pa0 += 8192; pa1 += 8192;
    }

#pragma unroll 1
    for (int ch = 0; ch < 8; ch++) {
        // x quad for chunk ch+1 (ch==7: dummy reload of chunk-7, in bounds)
        XLOAD(xa[0], px[0]); XLOAD(xa[1], px[1]);
        XLOAD(xa[2], px[2]); XLOAD(xa[3], px[3]);
        if (ch < 6) {                      // keep px in bounds for dummy reload
#pragma unroll
            for (int r = 0; r < 4; r++) px[r] += xadv;
        }

        char* abuf = &lds[(ch & 1) * BUF_SIZE];
        char* nbuf = &lds[((ch + 1) & 1) * BUF_SIZE];

        bf16x8 areg[3][4];
        auto aread = [&](int s, bf16x8 (&a)[4]) {
            int k = s / 3, bp = s - k * 3;
            int ki = k / 3, kj = k - ki * 3;
            int poff = (ki * HALO_W + kj) * 16;
            int aoff = (bp == 2) ? (G8_SIZE + poff) : (bp * 4 * CSTR + poff);
#pragma unroll
            for (int mi = 0; mi < 4; mi++)
                a[mi] = *reinterpret_cast<const bf16x8*>(abuf + P[mi] + aoff);
        };
        aread(0, areg[0]);
        aread(1, areg[1]);

#pragma unroll
        for (int s = 0; s < 27; s++) {
            // Post-drain queue: outstanding = 4 + 2s (+prologue on ch==0);
            // vmcnt(16) always retires the consumed pair, and the x quad by
            // s==8 (before the eval below).
            asm volatile("s_waitcnt vmcnt(16)");
            __builtin_amdgcn_sched_barrier(0);
            const int bs = s % 9;
#pragma unroll
            for (int mi = 0; mi < 4; mi++) {
                acc[mi][0] = __builtin_amdgcn_mfma_f32_16x16x32_bf16(areg[s % 3][mi], breg0[bs], acc[mi][0], 0, 0, 0);
                acc[mi][1] = __builtin_amdgcn_mfma_f32_16x16x32_bf16(areg[s % 3][mi], breg1[bs], acc[mi][1], 0, 0, 0);
            }
            // prefetch AFTER the MFMAs (R16-proven order)
            if (s + 2 < 27) aread(s + 2, areg[(s + 2) % 3]);
            // refill consumed slot (wraps past Bp end -> start; wrapped values
            // never consumed)
            BLOAD(breg0[bs], pa0);
            BLOAD(breg1[bs], pa1);
            pa0 += 8192; if (pa0 >= bend) pa0 -= BP_BYTES;
            pa1 += 8192; if (pa1 >= bend) pa1 -= BP_BYTES;
        }

        if (ch < 7 && valid) {
#pragma unroll
            for (int r = 0; r < 4; r++) {
                float va = inb ? xa[r] : 0.0f;
                int c = 2 * r + hi100;
                eval_store(va, &nbuf[c * CSTR + p * 16],
                           &nbuf[G8_SIZE + r * CSTR + p * 16 + hi100 * 8]);
            }
        }
        __syncthreads();   // full fence: drains vmem+lds, orders LDS reuse
    }

    // ---- epilogue: store + fused BN partial stats ----
    float psum[2] = {0.f, 0.f}, psq[2] = {0.f, 0.f};
#pragma unroll
    for (int ni = 0; ni < 2; ni++) {
        int o = obase + ni * 16;
#pragma unroll
        for (int mi = 0; mi < 4; mi++) {
            int lh = mi * 2 + (q >> 1);
            int lw0 = (q & 1) * 4;
            int lg = (th * TH + lh) * HW + tw * TW + lw0;
            float4 v;
            v.x = acc[mi][ni][0];
            v.y = acc[mi][ni][1];
            v.z = acc[mi][ni][2];
            v.w = acc[mi][ni][3];
            *reinterpret_cast<float4*>(&out[(size_t)(b * COUT + o) * L_ + lg]) = v;
            psum[ni] += v.x + v.y + v.z + v.w;
            psq[ni]  += v.x * v.x + v.y * v.y + v.z * v.z + v.w * v.w;
        }
    }
    // reduce across the 4 q-groups (lanes r15, r15+16, r15+32, r15+48 share o)
#pragma unroll
    for (int ni = 0; ni < 2; ni++) {
        psum[ni] += __shfl_xor(psum[ni], 16);
        psum[ni] += __shfl_xor(psum[ni], 32);
        psq[ni]  += __shfl_xor(psq[ni], 16);
        psq[ni]  += __shfl_xor(psq[ni], 32);
    }
    if (q == 0) {
#pragma unroll
        for (int ni = 0; ni < 2; ni++) {
            int o = obase + ni * 16;
            atomicAdd(&part[b * COUT + o], psum[ni]);
            atomicAdd(&part[1024 + b * COUT + o], psq[ni]);
        }
    }
}

__global__ __launch_bounds__(128) void k_final(const float* __restrict__ part,
                                               const float* __restrict__ gamma,
                                               const float* __restrict__ beta,
                                               float* __restrict__ ss) {
    int o = threadIdx.x;
    float sum = 0.f, sq = 0.f;
#pragma unroll
    for (int b = 0; b < 8; b++) {
        sum += part[b * COUT + o];
        sq  += part[1024 + b * COUT + o];
    }
    float n = (float)(8 * L_);
    float mean = sum / n;
    float var  = sq / n - mean * mean;
    float scale = gamma[o] * rsqrtf(var + 1e-5f);
    ss[o]        = scale;
    ss[COUT + o] = beta[o] - mean * scale;
}

__global__ __launch_bounds__(256) void k_norm(float* __restrict__ out,
                                              const float* __restrict__ ss) {
    const int n4 = 8 * COUT * L_ / 4;
    for (int i = blockIdx.x * 256 + threadIdx.x; i < n4; i += gridDim.x * 256) {
        int o = ((i * 4) / L_) & (COUT - 1);
        float sc = ss[o], sh = ss[COUT + o];
        float4 v = reinterpret_cast<float4*>(out)[i];
        v.x = fmaf(v.x, sc, sh);
        v.y = fmaf(v.y, sc, sh);
        v.z = fmaf(v.z, sc, sh);
        v.w = fmaf(v.w, sc, sh);
        reinterpret_cast<float4*>(out)[i] = v;
    }
}

extern "C" void kernel_launch(void* const* d_in, const int* in_sizes, int n_in,
                              void* d_out, int out_size, void* d_ws, size_t ws_size,
                              hipStream_t stream) {
    const float* x     = (const float*)d_in[0];
    const float* cp    = (const float*)d_in[1];
    const float* w     = (const float*)d_in[2];
    const float* gamma = (const float*)d_in[4];
    const float* beta  = (const float*)d_in[5];
    float* out = (float*)d_out;

    unsigned short* Bp = (unsigned short*)d_ws;
    float* part = (float*)((char*)d_ws + PART_OFF);
    float* ss   = (float*)((char*)d_ws + SS_OFF);

    k_packB<<<(COUT * KTOT + 255) / 256, 256, 0, stream>>>(cp, w, Bp, part);
    k_main<<<8 * 49, 256, 0, stream>>>(x, Bp, out, part);
    k_final<<<1, 128, 0, stream>>>(part, gamma, beta, ss);
    k_norm<<<2048, 256, 0, stream>>>(out, ss);
}